// Round 13
// baseline (1756.152 us; speedup 1.0000x reference)
//
#include <hip/hip_runtime.h>
#include <hip/hip_cooperative_groups.h>

namespace cg = cooperative_groups;

typedef unsigned short u16;
typedef unsigned int u32;
typedef __attribute__((ext_vector_type(8))) short short8v;
typedef __attribute__((ext_vector_type(4))) float f32x4;

#define GLD_LDS(g, l) __builtin_amdgcn_global_load_lds( \
    (const __attribute__((address_space(1))) void*)(g), \
    (__attribute__((address_space(3))) void*)(l), 16, 0, 0)

#define LOG2E 1.44269504f

__device__ __forceinline__ u16 f2bf(float f){
  union { float f; u32 u; } v; v.f = f;
  u32 r = v.u + 0x7FFFu + ((v.u >> 16) & 1u);
  return (u16)(r >> 16);
}
__device__ __forceinline__ float bf2f(u16 h){
  union { u32 u; float f; } v; v.u = ((u32)h) << 16;
  return v.f;
}
__device__ __forceinline__ u32 pk2(float a, float b){
  union { float f; u32 u; } x, y; x.f = a; y.f = b;
  return __builtin_amdgcn_perm(y.u + 0x8000u, x.u + 0x8000u, 0x07060302u);
}
__device__ __forceinline__ float sigm(float x){ return 1.f/(1.f+__expf(-x)); }
__device__ __forceinline__ float tanh_fast(float x){ return 1.f - 2.f/(1.f+__expf(2.f*x)); }

// ---------------------------------------------------------------------------
// prep: all weight matrices -> MFMA B-fragment layout, bf16, zero-padded.
__global__ void prep_kernel(const float* dih, const float* dhh,
    const float* eih, const float* ehh, const float* wq, const float* wk, const float* wv,
    u16* Dih, u16* Dhh, u16* Eih, u16* Ehh, u16* Qf, u16* Kf, u16* Vf)
{
  int idx = blockIdx.x*256 + threadIdx.x;
  const float* src; u16* dst; int KC, Kc, e;
  if      (idx < 27648){ src=dih; dst=Dih; KC=3; Kc=96; e=idx; }
  else if (idx < 55296){ src=dhh; dst=Dhh; KC=3; Kc=96; e=idx-27648; }
  else if (idx < 64512){ src=eih; dst=Eih; KC=2; Kc=48; e=idx-55296; }
  else if (idx < 73728){ src=ehh; dst=Ehh; KC=2; Kc=48; e=idx-64512; }
  else if (idx < 76800){ src=wq;  dst=Qf;  KC=2; Kc=48; e=idx-73728; }
  else if (idx < 79872){ src=wk;  dst=Kf;  KC=2; Kc=48; e=idx-76800; }
  else if (idx < 82944){ src=wv;  dst=Vf;  KC=2; Kc=48; e=idx-79872; }
  else return;
  int j = e & 7, ln = (e>>3) & 15, qd = (e>>7) & 3, tkc = e>>9;
  int kc = tkc % KC, nt = tkc / KC;
  int g = nt*16 + ln, k = kc*32 + qd*8 + j;
  dst[e] = (k < Kc) ? f2bf(src[g*Kc + k]) : (u16)0;
}

// ---------------------------------------------------------------------------
// setup: KV projection (blocks 0..503) + encoder (504..511).
__global__ __launch_bounds__(256) void setup_kernel(
    const float* past, const float* conv_w, const float* conv_b,
    const float* enc_b_ih, const float* enc_b_hh,
    const float* memory_past, const float* memory_fut,
    const float* bq, const float* bk, const float* bv,
    const u16* EihF, const u16* EhhF, const u16* WqF, const u16* WkF, const u16* WvF,
    float* stateP, float* qf, u16* qbB, u16* Kb, u16* Vc)
{
  __shared__ __align__(16) char SMEM[61440];
  const int tid = threadIdx.x, bx = blockIdx.x;
  const int wid = tid>>6, lane = tid&63, qd = lane>>4, ln = lane&15;
  f32x4 zf = {0.f,0.f,0.f,0.f};

  if (bx >= 504){
    // ======== ENCODER ========
    int eb = bx - 504;
    u16* sWih = (u16*)(SMEM);
    u16* sWhh = (u16*)(SMEM + 18432);
    u16* sWq  = (u16*)(SMEM + 36864);
    float* sCw = (float*)(SMEM + 43008);
    float* sCb = (float*)(SMEM + 44160);
    float* sPast = (float*)(SMEM + 44352);
    u16* sHbW = (u16*)(SMEM + 48448 + wid*2304);
    for (int i = wid; i < 18; i += 4) GLD_LDS((const char*)EihF + i*1024 + lane*16, SMEM + i*1024);
    for (int i = wid; i < 18; i += 4) GLD_LDS((const char*)EhhF + i*1024 + lane*16, SMEM + 18432 + i*1024);
    for (int i = wid; i < 6;  i += 4) GLD_LDS((const char*)WqF  + i*1024 + lane*16, SMEM + 36864 + i*1024);
    for (int i = tid; i < 288; i += 256) sCw[i] = conv_w[i];
    if (tid < 48) sCb[tid] = conv_b[tid];
    for (int i = tid; i < 1024; i += 256) sPast[i] = past[eb*1024 + i];
    __syncthreads();
    short8v aE[8][2];
    {
      const float* pr = &sPast[(wid*16 + ln)*16];
      for (int t = 0; t < 8; ++t)
        for (int kc = 0; kc < 2; ++kc){
          union { short8v v; u16 h[8]; } u;
          #pragma unroll
          for (int j = 0; j < 8; ++j){
            int d = kc*32 + qd*8 + j;
            float a = 0.f;
            if (d < 48){
              a = sCb[d];
              #pragma unroll
              for (int kt = 0; kt < 3; ++kt){
                int tau = t + kt - 1;
                if (tau >= 0 && tau < 8){
                  a += pr[tau*2+0]*sCw[d*6+kt];
                  a += pr[tau*2+1]*sCw[d*6+3+kt];
                }
              }
              a = fmaxf(a, 0.f);
            }
            u.h[j] = (d < 48) ? f2bf(a) : (u16)0;
          }
          aE[t][kc] = u.v;
        }
    }
    for (int i = lane; i < 576; i += 64) ((u32*)sHbW)[i] = 0;
    float biR[3],biZ[3],biN[3],bhR[3],bhZ[3],bhN[3];
    #pragma unroll
    for (int i = 0; i < 3; ++i){
      int d = i*16 + ln;
      biR[i]=enc_b_ih[d]; biZ[i]=enc_b_ih[48+d]; biN[i]=enc_b_ih[96+d];
      bhR[i]=enc_b_hh[d]; bhZ[i]=enc_b_hh[48+d]; bhN[i]=enc_b_hh[96+d];
    }
    float hreg[3][4];
    #pragma unroll
    for (int i=0;i<3;++i) for (int r=0;r<4;++r) hreg[i][r]=0.f;
    int r0 = eb*64 + wid*16;
    #pragma unroll 1
    for (int t = 0; t < 8; ++t){
      short8v aH0 = *(const short8v*)&sHbW[ln*72 + qd*8];
      short8v aH1 = *(const short8v*)&sHbW[ln*72 + 32 + qd*8];
      f32x4 gI[9], gH[9];
      #pragma unroll
      for (int nt = 0; nt < 9; ++nt){ gI[nt] = zf; gH[nt] = zf; }
      #pragma unroll
      for (int nt = 0; nt < 9; ++nt){
        gI[nt] = __builtin_amdgcn_mfma_f32_16x16x32_bf16(aE[t][0], *(const short8v*)&sWih[((nt*2+0)*4+qd)*128 + ln*8], gI[nt], 0,0,0);
        gI[nt] = __builtin_amdgcn_mfma_f32_16x16x32_bf16(aE[t][1], *(const short8v*)&sWih[((nt*2+1)*4+qd)*128 + ln*8], gI[nt], 0,0,0);
        gH[nt] = __builtin_amdgcn_mfma_f32_16x16x32_bf16(aH0, *(const short8v*)&sWhh[((nt*2+0)*4+qd)*128 + ln*8], gH[nt], 0,0,0);
        gH[nt] = __builtin_amdgcn_mfma_f32_16x16x32_bf16(aH1, *(const short8v*)&sWhh[((nt*2+1)*4+qd)*128 + ln*8], gH[nt], 0,0,0);
      }
      #pragma unroll
      for (int i3 = 0; i3 < 3; ++i3)
        #pragma unroll
        for (int r = 0; r < 4; ++r){
          float rr = sigm(gI[i3][r]+biR[i3] + gH[i3][r]+bhR[i3]);
          float zz = sigm(gI[i3+3][r]+biZ[i3] + gH[i3+3][r]+bhZ[i3]);
          float nn = tanh_fast(gI[i3+6][r]+biN[i3] + rr*(gH[i3+6][r]+bhN[i3]));
          float hv = (1.f-zz)*nn + zz*hreg[i3][r];
          hreg[i3][r] = hv;
          sHbW[(qd*4+r)*72 + i3*16 + ln] = f2bf(hv);
        }
    }
    #pragma unroll
    for (int i3 = 0; i3 < 3; ++i3)
      #pragma unroll
      for (int r = 0; r < 4; ++r)
        stateP[(r0+qd*4+r)*48 + i3*16 + ln] = hreg[i3][r];
    short8v aH0 = *(const short8v*)&sHbW[ln*72 + qd*8];
    short8v aH1 = *(const short8v*)&sHbW[ln*72 + 32 + qd*8];
    f32x4 q3[3];
    #pragma unroll
    for (int nt = 0; nt < 3; ++nt){
      q3[nt] = zf;
      q3[nt] = __builtin_amdgcn_mfma_f32_16x16x32_bf16(aH0, *(const short8v*)&sWq[((nt*2+0)*4+qd)*128 + ln*8], q3[nt], 0,0,0);
      q3[nt] = __builtin_amdgcn_mfma_f32_16x16x32_bf16(aH1, *(const short8v*)&sWq[((nt*2+1)*4+qd)*128 + ln*8], q3[nt], 0,0,0);
    }
    #pragma unroll
    for (int nt = 0; nt < 3; ++nt)
      #pragma unroll
      for (int r = 0; r < 4; ++r){
        int row = r0 + qd*4 + r, d = nt*16 + ln;
        float v = q3[nt][r] + bq[d];
        qf[row*48 + d] = v;
        qbB[row*64 + d] = f2bf(v * LOG2E);
      }
    #pragma unroll
    for (int r = 0; r < 4; ++r)
      if (ln < 8) *(u32*)&qbB[(r0+qd*4+r)*64 + 48 + ln*2] = 0;
  } else {
    // ======== KV projection ========
    u16* sWkF = (u16*)(SMEM);
    u16* sWvF = (u16*)(SMEM + 6144);
    u16* smp  = (u16*)(SMEM + 12288 + wid*2304);
    u16* smf  = (u16*)(SMEM + 21504 + wid*2304);
    u16* sKT  = (u16*)(SMEM + 30720);
    u16* sVT  = (u16*)(SMEM + 38912);
    for (int i = wid; i < 6; i += 4) GLD_LDS((const char*)WkF + i*1024 + lane*16, SMEM + i*1024);
    for (int i = wid; i < 6; i += 4) GLD_LDS((const char*)WvF + i*1024 + lane*16, SMEM + 6144 + i*1024);
    float bkv[3], bvv[3];
    #pragma unroll
    for (int nt = 0; nt < 3; ++nt){ bkv[nt] = bk[nt*16+ln]; bvv[nt] = bv[nt*16+ln]; }
    int ntile = (bx < 8) ? 2 : 1;
    for (int tt = 0; tt < ntile; ++tt){
      int tile = (tt == 0) ? bx : (504 + bx);
      int r0 = tile*64 + wid*16;
      for (int i = lane; i < 576; i += 64){ ((u32*)smp)[i] = 0; ((u32*)smf)[i] = 0; }
      for (int i = lane; i < 768; i += 64){
        int r = i/48, c = i - r*48;
        smp[r*72+c] = f2bf(memory_past[(size_t)r0*48 + i]);
        smf[r*72+c] = f2bf(memory_fut[(size_t)r0*48 + i]);
      }
      __syncthreads();
      short8v aP0 = *(const short8v*)&smp[ln*72 + qd*8];
      short8v aP1 = *(const short8v*)&smp[ln*72 + 32 + qd*8];
      short8v aF0 = *(const short8v*)&smf[ln*72 + qd*8];
      short8v aF1 = *(const short8v*)&smf[ln*72 + 32 + qd*8];
      f32x4 k3[3], v3[3];
      #pragma unroll
      for (int nt = 0; nt < 3; ++nt){ k3[nt] = zf; v3[nt] = zf; }
      #pragma unroll
      for (int nt = 0; nt < 3; ++nt){
        k3[nt] = __builtin_amdgcn_mfma_f32_16x16x32_bf16(aP0, *(const short8v*)&sWkF[((nt*2+0)*4+qd)*128 + ln*8], k3[nt], 0,0,0);
        k3[nt] = __builtin_amdgcn_mfma_f32_16x16x32_bf16(aP1, *(const short8v*)&sWkF[((nt*2+1)*4+qd)*128 + ln*8], k3[nt], 0,0,0);
        v3[nt] = __builtin_amdgcn_mfma_f32_16x16x32_bf16(aF0, *(const short8v*)&sWvF[((nt*2+0)*4+qd)*128 + ln*8], v3[nt], 0,0,0);
        v3[nt] = __builtin_amdgcn_mfma_f32_16x16x32_bf16(aF1, *(const short8v*)&sWvF[((nt*2+1)*4+qd)*128 + ln*8], v3[nt], 0,0,0);
      }
      for (int i = lane; i < 128; i += 64) ((u32*)sKT)[(wid*16 + (i>>3))*32 + 24 + (i&7)] = 0;
      #pragma unroll
      for (int nt = 0; nt < 3; ++nt)
        #pragma unroll
        for (int r = 0; r < 4; ++r){
          int keyl = wid*16 + qd*4 + r, d = nt*16 + ln;
          sKT[keyl*64 + d] = f2bf(k3[nt][r] + bkv[nt]);
          sVT[d*72 + keyl] = f2bf(v3[nt][r] + bvv[nt]);
        }
      __syncthreads();
      for (int i = tid; i < 512; i += 256)
        *(uint4*)((char*)(Kb + (size_t)tile*64*64) + i*16) = *(const uint4*)((char*)sKT + i*16);
      for (int i = tid; i < 384; i += 256){
        int d = i>>3, sub = i&7;
        *(uint4*)((char*)(Vc + ((size_t)((tile*64)>>8)*48 + d)*256 + ((tile*64)&255)) + sub*16)
            = *(const uint4*)((char*)sVT + d*144 + sub*16);
      }
      __syncthreads();
    }
  }
}

// ---------------------------------------------------------------------------
// iter: persistent over iterations [it0, it1). grid 256 = 16 rg(32 rows) x 16 ch.
// q held in LDS across iterations; grid.sync() between iterations (cooperative).
// Fallback: host launches per-iteration (it1 = it0+1 -> no sync executed).
__global__ __launch_bounds__(256, 1) void iter_kernel(int it0, int it1,
    const u16* Kb, const u16* Vc, const u16* WqF, const float* bq,
    const float* qfIn, float* qfA, float* qfB, float* pred,
    float* m0b, float* l0b, float* a0b, float* m1b, float* l1b, float* a1b)
{
  // LDS: [0,26624) union{ sRed 4x1536f | sMg 4x1600f }; [26624,45056) sp8;
  // 45056 sQ(4096); 49152 sWc(2048); 51200 sLg(128); 51332 sCb(4604); 55936 sQf(6144)
  __shared__ __align__(16) char SMEM[62080];
  u16*   sQ  = (u16*)(SMEM + 45056);
  float* sWc = (float*)(SMEM + 49152);
  float* sLg = (float*)(SMEM + 51200);
  u16*   sCb = (u16*)(SMEM + 51332);
  float* sQf = (float*)(SMEM + 55936);
  const int tid = threadIdx.x, bx = blockIdx.x;
  const int wid = tid>>6, lane = tid&63, qd = lane>>4, ln = lane&15;
  const int rg = bx>>4, ch = bx&15;
  const int rowbase = rg*32;
  f32x4 zf = {0.f,0.f,0.f,0.f};

  // launch-start: load q (fp32 + bf16*log2e) into LDS
  for (int i = tid; i < 1536; i += 256){
    float v = qfIn[rowbase*48 + i];
    sQf[i] = v;
    int row = i/48, d = i - row*48;
    sQ[row*64 + d] = f2bf(v * LOG2E);
  }
  { int r2 = tid>>3, p = tid&7; ((u32*)sQ)[r2*32 + 24 + p] = 0; }
  __syncthreads();

  #pragma unroll 1
  for (int it = it0; it < it1; ++it){
    const float* mP = (it&1) ? m0b : m1b;
    const float* lP = (it&1) ? l0b : l1b;
    const float* aP = (it&1) ? a0b : a1b;
    float* mC = (it&1) ? m1b : m0b;
    float* lC = (it&1) ? l1b : l0b;
    float* aC = (it&1) ? a1b : a0b;
    float* qOut = (it&1) ? qfB : qfA;

    if (it > 0){
      // ---- combine prev partials ----
      float* sRed = (float*)SMEM;
      {
        int row = tid>>3, jj = tid&7, grow = rowbase + row;
        float m0 = mP[grow*16 + jj*2], m1 = mP[grow*16 + jj*2+1];
        float l0 = lP[grow*16 + jj*2], l1 = lP[grow*16 + jj*2+1];
        float mg = fmaxf(m0, m1);
        #pragma unroll
        for (int k = 1; k < 8; k <<= 1) mg = fmaxf(mg, __shfl_xor(mg, k));
        float w0 = exp2f(m0 - mg), w1 = exp2f(m1 - mg);
        float wl = w0*l0 + w1*l1;
        #pragma unroll
        for (int k = 1; k < 8; k <<= 1) wl += __shfl_xor(wl, k);
        sWc[row*16 + jj*2] = w0; sWc[row*16 + jj*2+1] = w1;
        if (jj == 0) sLg[row] = wl;
      }
      __syncthreads();
      {
        f32x4 accv[6];
        #pragma unroll
        for (int i = 0; i < 6; ++i) accv[i] = zf;
        #pragma unroll
        for (int ci = 0; ci < 4; ++ci){
          int c = wid*4 + ci;
          const f32x4* slab = (const f32x4*)(aP + ((size_t)c*512 + rowbase)*48);
          #pragma unroll
          for (int i = 0; i < 6; ++i){
            f32x4 v = slab[i*64 + lane];
            int rr = (i*64 + lane)/12;
            float w = sWc[rr*16 + c];
            accv[i][0] += w*v[0]; accv[i][1] += w*v[1];
            accv[i][2] += w*v[2]; accv[i][3] += w*v[3];
          }
        }
        float* red = sRed + wid*1536;
        #pragma unroll
        for (int i = 0; i < 6; ++i)
          *(f32x4*)&red[(i*64 + lane)*4] = accv[i];
      }
      __syncthreads();
      {
        int row = tid>>3, jj = tid&7, grow = rowbase + row;
        float lg = sLg[row];
        int base = row*48 + jj*6;
        #pragma unroll
        for (int d6 = 0; d6 < 6; ++d6){
          int d = jj*6 + d6;
          float s = sRed[base+d6] + sRed[1536+base+d6] + sRed[3072+base+d6] + sRed[4608+base+d6];
          float a = s / lg;
          if (ch == 0) pred[(size_t)(grow*20 + (it-1))*48 + d] = a;
          sCb[row*72 + d] = f2bf(sQf[row*48 + d] + a);
        }
        ((u32*)&sCb[row*72 + 48])[jj] = 0;
      }
      __syncthreads();
      // q projection (waves 0,1); pad sQ (waves 2,3)
      if (wid < 2){
        short8v ac0 = *(const short8v*)&sCb[(wid*16+ln)*72 + qd*8];
        short8v ac1 = *(const short8v*)&sCb[(wid*16+ln)*72 + 32 + qd*8];
        f32x4 q3[3];
        #pragma unroll
        for (int nt = 0; nt < 3; ++nt){
          q3[nt] = zf;
          q3[nt] = __builtin_amdgcn_mfma_f32_16x16x32_bf16(ac0, *(const short8v*)&WqF[((nt*2+0)*4+qd)*128 + ln*8], q3[nt], 0,0,0);
          q3[nt] = __builtin_amdgcn_mfma_f32_16x16x32_bf16(ac1, *(const short8v*)&WqF[((nt*2+1)*4+qd)*128 + ln*8], q3[nt], 0,0,0);
        }
        #pragma unroll
        for (int nt = 0; nt < 3; ++nt)
          #pragma unroll
          for (int r = 0; r < 4; ++r){
            int lr = wid*16 + qd*4 + r, d = nt*16 + ln;
            float v = q3[nt][r] + bq[d];
            sQf[lr*48 + d] = v;
            if (ch == 0) qOut[(rowbase + lr)*48 + d] = v;
            sQ[lr*64 + d] = f2bf(v * LOG2E);
          }
      } else {
        for (int i = tid-128; i < 256; i += 128){
          int r2 = i>>3, p = i&7;
          ((u32*)&sQ[r2*64 + 48])[p] = 0;
        }
      }
      __syncthreads();
    }

    // ---- flash: wave = 32 rows x 512 keys (8 kt of 64) ----
    const int wslice = ch*2048 + wid*512;
    u16* sp8 = (u16*)(SMEM + 26624);
    short8v aq[2][2];
    #pragma unroll
    for (int rt = 0; rt < 2; ++rt)
      #pragma unroll
      for (int kc = 0; kc < 2; ++kc)
        aq[rt][kc] = *(const short8v*)&sQ[(rt*16+ln)*64 + kc*32 + qd*8];
    f32x4 acc[2][3];
    #pragma unroll
    for (int rt = 0; rt < 2; ++rt) for (int dt = 0; dt < 3; ++dt) acc[rt][dt] = zf;
    float mrun[2] = {-3.0e38f, -3.0e38f}, lrun[2] = {0.f, 0.f};
    u16* spb[2] = { sp8 + (wid*2+0)*1152, sp8 + (wid*2+1)*1152 };

    #pragma unroll
    for (int kt = 0; kt < 8; ++kt){
      const int tb = wslice + kt*64;
      const u16* kb = Kb + (size_t)tb*64;
      const u16* vb = Vc + (size_t)(tb>>8)*48*256 + (tb & 255);
      short8v kf[4][2], vf[2][3];
      #pragma unroll
      for (int nt = 0; nt < 4; ++nt)
        #pragma unroll
        for (int kc = 0; kc < 2; ++kc)
          kf[nt][kc] = *(const short8v*)&kb[(nt*16+ln)*64 + kc*32 + qd*8];
      #pragma unroll
      for (int kc = 0; kc < 2; ++kc)
        #pragma unroll
        for (int dt = 0; dt < 3; ++dt)
          vf[kc][dt] = *(const short8v*)&vb[(dt*16+ln)*256 + kc*32 + qd*8];
      f32x4 s[2][4];
      #pragma unroll
      for (int rt = 0; rt < 2; ++rt)
        #pragma unroll
        for (int nt = 0; nt < 4; ++nt){
          f32x4 z = zf;
          z = __builtin_amdgcn_mfma_f32_16x16x32_bf16(kf[nt][0], aq[rt][0], z, 0,0,0);
          z = __builtin_amdgcn_mfma_f32_16x16x32_bf16(kf[nt][1], aq[rt][1], z, 0,0,0);
          s[rt][nt] = z;
        }
      #pragma unroll
      for (int rt = 0; rt < 2; ++rt){
        float vmax = fmaxf(fmaxf(fmaxf(s[rt][0][0], s[rt][0][1]), fmaxf(s[rt][0][2], s[rt][0][3])),
                     fmaxf(fmaxf(s[rt][1][0], s[rt][1][1]), fmaxf(s[rt][1][2], s[rt][1][3])));
        vmax = fmaxf(vmax, fmaxf(fmaxf(fmaxf(s[rt][2][0], s[rt][2][1]), fmaxf(s[rt][2][2], s[rt][2][3])),
                     fmaxf(fmaxf(s[rt][3][0], s[rt][3][1]), fmaxf(s[rt][3][2], s[rt][3][3]))));
        vmax = fmaxf(vmax, __shfl_xor(vmax, 16));
        vmax = fmaxf(vmax, __shfl_xor(vmax, 32));
        float mnew = fmaxf(mrun[rt], vmax);
        float alpha = exp2f(mrun[rt] - mnew);
        mrun[rt] = mnew;
        u16* sp = spb[rt];
        float lsum = 0.f;
        #pragma unroll
        for (int nt = 0; nt < 4; ++nt){
          float p0 = exp2f(s[rt][nt][0]-mnew), p1 = exp2f(s[rt][nt][1]-mnew);
          float p2 = exp2f(s[rt][nt][2]-mnew), p3 = exp2f(s[rt][nt][3]-mnew);
          lsum += (p0+p1)+(p2+p3);
          uint2 pk; pk.x = pk2(p0,p1); pk.y = pk2(p2,p3);
          *(uint2*)&sp[ln*72 + nt*16 + qd*4] = pk;
        }
        lsum += __shfl_xor(lsum, 16);
        lsum += __shfl_xor(lsum, 32);
        lrun[rt] = lrun[rt]*alpha + lsum;
        #pragma unroll
        for (int dt = 0; dt < 3; ++dt){
          acc[rt][dt][0] *= alpha; acc[rt][dt][1] *= alpha;
          acc[rt][dt][2] *= alpha; acc[rt][dt][3] *= alpha;
        }
        short8v pb0 = *(const short8v*)&sp[ln*72 + qd*8];
        short8v pb1 = *(const short8v*)&sp[ln*72 + 32 + qd*8];
        #pragma unroll
        for (int dt = 0; dt < 3; ++dt){
          acc[rt][dt] = __builtin_amdgcn_mfma_f32_16x16x32_bf16(vf[0][dt], pb0, acc[rt][dt], 0,0,0);
          acc[rt][dt] = __builtin_amdgcn_mfma_f32_16x16x32_bf16(vf[1][dt], pb1, acc[rt][dt], 0,0,0);
        }
      }
    }
    // ---- 4-wave merge -> one partial per (row, chunk), slab layout ----
    __syncthreads();
    float* sMg = (float*)SMEM;
    #pragma unroll
    for (int rt = 0; rt < 2; ++rt)
      #pragma unroll
      for (int dt = 0; dt < 3; ++dt)
        #pragma unroll
        for (int r = 0; r < 4; ++r)
          sMg[wid*1600 + (rt*16+ln)*50 + dt*16 + qd*4 + r] = acc[rt][dt][r];
    if (lane < 16){
      sMg[wid*1600 + ln*50 + 48] = mrun[0]; sMg[wid*1600 + ln*50 + 49] = lrun[0];
      sMg[wid*1600 + (16+ln)*50 + 48] = mrun[1]; sMg[wid*1600 + (16+ln)*50 + 49] = lrun[1];
    }
    __syncthreads();
    {
      int row = tid>>3, jj = tid&7, grow = rowbase + row;
      float m0 = sMg[row*50+48], m1 = sMg[1600+row*50+48];
      float m2 = sMg[3200+row*50+48], m3 = sMg[4800+row*50+48];
      float mg = fmaxf(fmaxf(m0,m1), fmaxf(m2,m3));
      float e0 = exp2f(m0-mg), e1 = exp2f(m1-mg), e2 = exp2f(m2-mg), e3 = exp2f(m3-mg);
      float lg = e0*sMg[row*50+49] + e1*sMg[1600+row*50+49]
               + e2*sMg[3200+row*50+49] + e3*sMg[4800+row*50+49];
      if (jj == 0){ mC[grow*16 + ch] = mg; lC[grow*16 + ch] = lg; }
      int d0 = jj*6;
      #pragma unroll
      for (int d6 = 0; d6 < 6; ++d6){
        int d = d0 + d6;
        aC[((size_t)ch*512 + grow)*48 + d] =
            e0*sMg[row*50+d] + e1*sMg[1600+row*50+d]
          + e2*sMg[3200+row*50+d] + e3*sMg[4800+row*50+d];
      }
    }
    __syncthreads();   // LDS reuse guard before next iteration's combine
    if (it + 1 < it1){
      __threadfence();
      cg::this_grid().sync();
    }
  }
}

// ---------------------------------------------------------------------------
// decoder: 12-step GRU(96); 640 blocks x 384 thr (6 waves); gates split 6-way
// (one 16-dim slice per wave, 3 ntiles each, frags in VGPRs). [r10: 54.5us]
__global__ __launch_bounds__(384) void dec_kernel(
    const u16* Dihf, const u16* Dhhf, const float* b_ih, const float* b_hh,
    const float* stateP, const float* pred, const float* obs,
    const float* mF, const float* lF, const float* aF,
    const float* fc_w, const float* fc_b, float* out)
{
  __shared__ __align__(16) u16 sx[2][16*104];
  __shared__ float sPx[2][6][16], sPy[2][6][16];
  const int tid = threadIdx.x, bx = blockIdx.x;
  const int wid = tid>>6, lane = tid&63, qd = lane>>4, ln = lane&15;
  const int rw = bx*16;
  f32x4 zf = {0.f,0.f,0.f,0.f};

  for (int i = tid; i < 1536; i += 384){
    int r = i/96, k = i - r*96;
    int row = rw + r, b20 = row/20;
    float v = (k < 48) ? stateP[b20*48 + k] : pred[(size_t)row*48 + (k-48)];
    sx[0][r*104 + k] = f2bf(v);
  }
  if (tid < 48){
    int r19 = (19 - (rw % 20)) % 20;
    if (r19 < 16){
      int b = (rw + r19)/20;
      float mg = -3.0e38f, mv[16];
      #pragma unroll
      for (int c = 0; c < 16; ++c){ mv[c] = mF[b*16 + c]; mg = fmaxf(mg, mv[c]); }
      float num = 0.f, den = 0.f;
      #pragma unroll
      for (int c = 0; c < 16; ++c){
        float w = exp2f(mv[c] - mg);
        den += w * lF[b*16 + c];
        num += w * aF[((size_t)c*512 + b)*48 + tid];
      }
      sx[0][r19*104 + 48 + tid] = f2bf(num/den);
    }
  }
  short8v whh[3][3];
  #pragma unroll
  for (int g = 0; g < 3; ++g)
    #pragma unroll
    for (int kc = 0; kc < 3; ++kc)
      whh[g][kc] = *(const short8v*)&Dhhf[(((g*6+wid)*3+kc)*4+qd)*128 + ln*8];
  const int d = wid*16 + ln;
  float biR=b_ih[d], biZ=b_ih[96+d], biN=b_ih[192+d];
  float bhR=b_hh[d], bhZ=b_hh[96+d], bhN=b_hh[192+d];
  float fw0=fc_w[d], fw1=fc_w[96+d];
  float hold[4] = {0.f,0.f,0.f,0.f};
  float fcb0 = fc_b[0], fcb1 = fc_b[1];
  float pres0 = 0.f, pres1 = 0.f;
  if (wid == 0 && lane < 16){
    int b20 = (rw + lane)/20;
    pres0 = obs[b20*16 + 14];
    pres1 = obs[b20*16 + 15];
  }
  __syncthreads();

  #pragma unroll 1
  for (int t = 0; t < 12; ++t){
    const u16* sr = sx[t&1];
    u16* sw = sx[(t+1)&1];
    short8v xa0 = *(const short8v*)&sr[ln*104 + qd*8];
    short8v xa1 = *(const short8v*)&sr[ln*104 + 32 + qd*8];
    short8v xa2 = *(const short8v*)&sr[ln*104 + 64 + qd*8];
    f32x4 acc[3] = {zf, zf, zf};
    if (t == 0){
      #pragma unroll
      for (int g = 0; g < 3; ++g){
        int nt = g*6 + wid;
        acc[g] = __builtin_amdgcn_mfma_f32_16x16x32_bf16(xa0, *(const short8v*)&Dihf[((nt*3+0)*4+qd)*128 + ln*8], acc[g], 0,0,0);
        acc[g] = __builtin_amdgcn_mfma_f32_16x16x32_bf16(xa1, *(const short8v*)&Dihf[((nt*3+1)*4+qd)*128 + ln*8], acc[g], 0,0,0);
        acc[g] = __builtin_amdgcn_mfma_f32_16x16x32_bf16(xa2, *(const short8v*)&Dihf[((nt*3+2)*4+qd)*128 + ln*8], acc[g], 0,0,0);
      }
    } else {
      #pragma unroll
      for (int g = 0; g < 3; ++g){
        acc[g] = __builtin_amdgcn_mfma_f32_16x16x32_bf16(xa0, whh[g][0], acc[g], 0,0,0);
        acc[g] = __builtin_amdgcn_mfma_f32_16x16x32_bf16(xa1, whh[g][1], acc[g], 0,0,0);
        acc[g] = __builtin_amdgcn_mfma_f32_16x16x32_bf16(xa2, whh[g][2], acc[g], 0,0,0);
      }
    }
    float px[4], py[4];
    #pragma unroll
    for (int r = 0; r < 4; ++r){
      float rr = sigm(acc[0][r] + biR + bhR);
      float zz = sigm(acc[1][r] + biZ + bhZ);
      float nn = (t == 0) ? tanh_fast(acc[2][r] + biN + rr*bhN)
                          : tanh_fast(biN + rr*(acc[2][r] + bhN));
      float hv = (1.f-zz)*nn + zz*hold[r];
      hold[r] = hv;
      sw[(qd*4+r)*104 + d] = f2bf(hv);
      px[r] = fw0*hv;
      py[r] = fw1*hv;
    }
    #pragma unroll
    for (int msk = 8; msk >= 1; msk >>= 1)
      #pragma unroll
      for (int r = 0; r < 4; ++r){
        px[r] += __shfl_xor(px[r], msk);
        py[r] += __shfl_xor(py[r], msk);
      }
    if (ln == 0){
      #pragma unroll
      for (int r = 0; r < 4; ++r){
        sPx[t&1][wid][qd*4+r] = px[r];
        sPy[t&1][wid][qd*4+r] = py[r];
      }
    }
    __syncthreads();
    if (wid == 0 && lane < 16){
      float fx = 0.f, fy = 0.f;
      #pragma unroll
      for (int w = 0; w < 6; ++w){ fx += sPx[t&1][w][lane]; fy += sPy[t&1][w][lane]; }
      pres0 += fx + fcb0;
      pres1 += fy + fcb1;
      out[((size_t)(rw + lane)*12 + t)*2 + 0] = pres0;
      out[((size_t)(rw + lane)*12 + t)*2 + 1] = pres1;
    }
  }
}

// ---------------------------------------------------------------------------
extern "C" void kernel_launch(void* const* d_in, const int* in_sizes, int n_in,
                              void* d_out, int out_size, void* d_ws, size_t ws_size,
                              hipStream_t stream)
{
  const float* past        = (const float*)d_in[0];
  const float* obs         = (const float*)d_in[1];
  const float* conv_w      = (const float*)d_in[2];
  const float* conv_b      = (const float*)d_in[3];
  const float* enc_w_ih    = (const float*)d_in[4];
  const float* enc_w_hh    = (const float*)d_in[5];
  const float* enc_b_ih    = (const float*)d_in[6];
  const float* enc_b_hh    = (const float*)d_in[7];
  const float* memory_past = (const float*)d_in[8];
  const float* memory_fut  = (const float*)d_in[9];
  const float* Wq = (const float*)d_in[10];
  const float* bq = (const float*)d_in[11];
  const float* Wk = (const float*)d_in[12];
  const float* bk = (const float*)d_in[13];
  const float* Wv = (const float*)d_in[14];
  const float* bv = (const float*)d_in[15];
  const float* dec_w_ih = (const float*)d_in[16];
  const float* dec_w_hh = (const float*)d_in[17];
  const float* dec_b_ih = (const float*)d_in[18];
  const float* dec_b_hh = (const float*)d_in[19];
  const float* fc_w = (const float*)d_in[20];
  const float* fc_b = (const float*)d_in[21];
  float* out = (float*)d_out;

  char* ws = (char*)d_ws;
  size_t off = 0;
  auto alloc = [&](size_t bytes){ void* p = ws + off; off += (bytes + 255) & ~(size_t)255; return p; };
  float* stateP = (float*)alloc(512*48*4);
  float* qfA    = (float*)alloc(512*48*4);
  float* qfB    = (float*)alloc(512*48*4);
  u16*   qbB    = (u16*)alloc(512*64*2);
  float* m0b = (float*)alloc(512*16*4);
  float* l0b = (float*)alloc(512*16*4);
  float* a0b = (float*)alloc((size_t)512*16*48*4);
  float* m1b = (float*)alloc(512*16*4);
  float* l1b = (float*)alloc(512*16*4);
  float* a1b = (float*)alloc((size_t)512*16*48*4);
  float* pred = (float*)alloc((size_t)10240*48*4);
  u16*   Kb   = (u16*)alloc((size_t)32768*64*2);
  u16*   Vc   = (u16*)alloc((size_t)32768*48*2);
  u16*   Dihf = (u16*)alloc(27648*2);
  u16*   Dhhf = (u16*)alloc(27648*2);
  u16*   EihF = (u16*)alloc(9216*2);
  u16*   EhhF = (u16*)alloc(9216*2);
  u16*   WqF  = (u16*)alloc(3072*2);
  u16*   WkF  = (u16*)alloc(3072*2);
  u16*   WvF  = (u16*)alloc(3072*2);

  prep_kernel<<<324, 256, 0, stream>>>(dec_w_ih, dec_w_hh, enc_w_ih, enc_w_hh,
                                       Wq, Wk, Wv, Dihf, Dhhf, EihF, EhhF, WqF, WkF, WvF);

  setup_kernel<<<512, 256, 0, stream>>>(
      past, conv_w, conv_b, enc_b_ih, enc_b_hh, memory_past, memory_fut,
      bq, bk, bv, EihF, EhhF, WqF, WkF, WvF,
      stateP, qfA, qbB, Kb, Vc);

  // cooperative persistent iterations; fallback to per-iteration launches
  {
    int it0 = 0, it1 = 20;
    const u16* Kb_ = Kb; const u16* Vc_ = Vc; const u16* WqF_ = WqF;
    const float* bq_ = bq; const float* qin = qfA;
    float* qfA_ = qfA; float* qfB_ = qfB; float* pred_ = pred;
    float* m0_ = m0b; float* l0_ = l0b; float* a0_ = a0b;
    float* m1_ = m1b; float* l1_ = l1b; float* a1_ = a1b;
    void* args[] = { &it0, &it1, &Kb_, &Vc_, &WqF_, &bq_, &qin,
                     &qfA_, &qfB_, &pred_, &m0_, &l0_, &a0_, &m1_, &l1_, &a1_ };
    hipError_t e = hipLaunchCooperativeKernel((const void*)iter_kernel,
                                              dim3(256), dim3(256), args, 0, stream);
    if (e != hipSuccess){
      for (int it = 0; it < 20; ++it){
        const float* q_in = (it == 0) ? qfA : (((it-1)&1) ? qfB : qfA);
        iter_kernel<<<256, 256, 0, stream>>>(it, it+1, Kb, Vc, WqF, bq,
            q_in, qfA, qfB, pred, m0b, l0b, a0b, m1b, l1b, a1b);
      }
    }
  }

  // it=19 wrote buffer index 1 -> dec consumes m1b/l1b/a1b
  dec_kernel<<<640, 384, 0, stream>>>(Dihf, Dhhf, dec_b_ih, dec_b_hh,
      stateP, pred, obs, m1b, l1b, a1b, fc_w, fc_b, out);
}

// Round 14
// 584.200 us; speedup vs baseline: 3.0061x; 3.0061x over previous
//
#include <hip/hip_runtime.h>

typedef unsigned short u16;
typedef unsigned int u32;
typedef __attribute__((ext_vector_type(8))) short short8v;
typedef __attribute__((ext_vector_type(4))) float f32x4;

#define GLD_LDS(g, l) __builtin_amdgcn_global_load_lds( \
    (const __attribute__((address_space(1))) void*)(g), \
    (__attribute__((address_space(3))) void*)(l), 16, 0, 0)

#define LOG2E 1.44269504f

__device__ __forceinline__ u16 f2bf(float f){
  union { float f; u32 u; } v; v.f = f;
  u32 r = v.u + 0x7FFFu + ((v.u >> 16) & 1u);
  return (u16)(r >> 16);
}
__device__ __forceinline__ float bf2f(u16 h){
  union { u32 u; float f; } v; v.u = ((u32)h) << 16;
  return v.f;
}
__device__ __forceinline__ float bflo(u32 x){
  union { u32 u; float f; } v; v.u = x << 16; return v.f;
}
__device__ __forceinline__ float bfhi(u32 x){
  union { u32 u; float f; } v; v.u = x & 0xFFFF0000u; return v.f;
}
__device__ __forceinline__ u32 pk2(float a, float b){
  union { float f; u32 u; } x, y; x.f = a; y.f = b;
  return __builtin_amdgcn_perm(y.u + 0x8000u, x.u + 0x8000u, 0x07060302u);
}
__device__ __forceinline__ float sigm(float x){ return 1.f/(1.f+__expf(-x)); }
__device__ __forceinline__ float tanh_fast(float x){ return 1.f - 2.f/(1.f+__expf(2.f*x)); }

// ---------------------------------------------------------------------------
// prep: all weight matrices -> MFMA B-fragment layout, bf16, zero-padded.
__global__ void prep_kernel(const float* dih, const float* dhh,
    const float* eih, const float* ehh, const float* wq, const float* wk, const float* wv,
    u16* Dih, u16* Dhh, u16* Eih, u16* Ehh, u16* Qf, u16* Kf, u16* Vf)
{
  int idx = blockIdx.x*256 + threadIdx.x;
  const float* src; u16* dst; int KC, Kc, e;
  if      (idx < 27648){ src=dih; dst=Dih; KC=3; Kc=96; e=idx; }
  else if (idx < 55296){ src=dhh; dst=Dhh; KC=3; Kc=96; e=idx-27648; }
  else if (idx < 64512){ src=eih; dst=Eih; KC=2; Kc=48; e=idx-55296; }
  else if (idx < 73728){ src=ehh; dst=Ehh; KC=2; Kc=48; e=idx-64512; }
  else if (idx < 76800){ src=wq;  dst=Qf;  KC=2; Kc=48; e=idx-73728; }
  else if (idx < 79872){ src=wk;  dst=Kf;  KC=2; Kc=48; e=idx-76800; }
  else if (idx < 82944){ src=wv;  dst=Vf;  KC=2; Kc=48; e=idx-79872; }
  else return;
  int j = e & 7, ln = (e>>3) & 15, qd = (e>>7) & 3, tkc = e>>9;
  int kc = tkc % KC, nt = tkc / KC;
  int g = nt*16 + ln, k = kc*32 + qd*8 + j;
  dst[e] = (k < Kc) ? f2bf(src[g*Kc + k]) : (u16)0;
}

// ---------------------------------------------------------------------------
// setup: KV projection (blocks 0..479, 512 tiles) + encoder (480..511, 16 rows each).
// Encoder: phase A computes gI[t] for all 8 t in parallel (4 waves x 2 t);
// phase B runs the 8-step GRU with dec-style gate-slice waves (3 waves).
__global__ __launch_bounds__(256) void setup_kernel(
    const float* past, const float* conv_w, const float* conv_b,
    const float* enc_b_ih, const float* enc_b_hh,
    const float* memory_past, const float* memory_fut,
    const float* bq, const float* bk, const float* bv,
    const u16* EihF, const u16* EhhF, const u16* WqF, const u16* WkF, const u16* WvF,
    float* stateP, float* qf, u16* qbB, u16* Kb, u16* Vc)
{
  __shared__ __align__(16) char SMEM[61440];
  const int tid = threadIdx.x, bx = blockIdx.x;
  const int wid = tid>>6, lane = tid&63, qd = lane>>4, ln = lane&15;
  f32x4 zf = {0.f,0.f,0.f,0.f};

  if (bx >= 480){
    // ======== ENCODER: 16 rows per block ========
    const int eb = bx - 480;
    const int r0 = eb*16;
    u16*   sWf  = (u16*)(SMEM);            // 18432 B: WihF (A) then WhhF (B)
    u16*   gIb  = (u16*)(SMEM + 18432);    // 36864 B: gI bf16 [8][16][144]
    u16*   sHb0 = (u16*)(SMEM + 55296);    // 2304 B
    u16*   sHb1 = (u16*)(SMEM + 57600);    // 2304 B (overlaps sCw/sCb, phase-B only)
    float* sCw  = (float*)(SMEM + 57600);  // 1152 B (phase A)
    float* sCb  = (float*)(SMEM + 58752);  // 192 B  (phase A)
    float* sPast= (float*)(SMEM + 58944);  // 1024 B (phase A)

    // ---- phase A: stage WihF, conv -> gI for 2 timesteps per wave ----
    for (int i = wid; i < 18; i += 4) GLD_LDS((const char*)EihF + i*1024 + lane*16, (char*)sWf + i*1024);
    for (int i = tid; i < 288; i += 256) sCw[i] = conv_w[i];
    if (tid < 48) sCb[tid] = conv_b[tid];
    for (int i = tid; i < 256; i += 256) sPast[i] = past[r0*16 + i];
    __syncthreads();
    #pragma unroll
    for (int tt = 0; tt < 2; ++tt){
      int t = wid*2 + tt;
      short8v aE[2];
      {
        const float* pr = &sPast[ln*16];
        #pragma unroll
        for (int kc = 0; kc < 2; ++kc){
          union { short8v v; u16 h[8]; } u;
          #pragma unroll
          for (int j = 0; j < 8; ++j){
            int d = kc*32 + qd*8 + j;
            float a = 0.f;
            if (d < 48){
              a = sCb[d];
              #pragma unroll
              for (int kt = 0; kt < 3; ++kt){
                int tau = t + kt - 1;
                if (tau >= 0 && tau < 8){
                  a += pr[tau*2+0]*sCw[d*6+kt];
                  a += pr[tau*2+1]*sCw[d*6+3+kt];
                }
              }
              a = fmaxf(a, 0.f);
            }
            u.h[j] = (d < 48) ? f2bf(a) : (u16)0;
          }
          aE[kc] = u.v;
        }
      }
      f32x4 gI[9];
      #pragma unroll
      for (int nt = 0; nt < 9; ++nt) gI[nt] = zf;
      #pragma unroll
      for (int nt = 0; nt < 9; ++nt){
        gI[nt] = __builtin_amdgcn_mfma_f32_16x16x32_bf16(aE[0], *(const short8v*)&sWf[((nt*2+0)*4+qd)*128 + ln*8], gI[nt], 0,0,0);
        gI[nt] = __builtin_amdgcn_mfma_f32_16x16x32_bf16(aE[1], *(const short8v*)&sWf[((nt*2+1)*4+qd)*128 + ln*8], gI[nt], 0,0,0);
      }
      #pragma unroll
      for (int nt = 0; nt < 9; ++nt)
        #pragma unroll
        for (int r = 0; r < 4; ++r)
          gIb[t*2304 + (qd*4+r)*144 + nt*16 + ln] = f2bf(gI[nt][r]);
    }
    __syncthreads();
    // ---- restage WhhF; zero h buffers ----
    for (int i = wid; i < 18; i += 4) GLD_LDS((const char*)EhhF + i*1024 + lane*16, (char*)sWf + i*1024);
    for (int i = tid; i < 1152; i += 256) ((u32*)sHb0)[i] = 0;   // covers sHb0+sHb1
    __syncthreads();

    // ---- phase B: 8-step GRU; wave g owns dim slice g*16..+16 (g<3) ----
    const int g = wid;
    float biR=0, biZ=0, biN=0, bhR=0, bhZ=0, bhN=0;
    if (g < 3){
      int d = g*16 + ln;
      biR = enc_b_ih[d]; biZ = enc_b_ih[48+d]; biN = enc_b_ih[96+d];
      bhR = enc_b_hh[d]; bhZ = enc_b_hh[48+d]; bhN = enc_b_hh[96+d];
    }
    float hold[4] = {0.f,0.f,0.f,0.f};
    #pragma unroll 1
    for (int t = 0; t < 8; ++t){
      u16* sr = (t & 1) ? sHb1 : sHb0;
      u16* sw = (t & 1) ? sHb0 : sHb1;
      if (g < 3){
        short8v aH0 = *(const short8v*)&sr[ln*72 + qd*8];
        short8v aH1 = *(const short8v*)&sr[ln*72 + 32 + qd*8];
        f32x4 aR = zf, aZ = zf, aN = zf;
        aR = __builtin_amdgcn_mfma_f32_16x16x32_bf16(aH0, *(const short8v*)&sWf[(((g  )*2+0)*4+qd)*128 + ln*8], aR, 0,0,0);
        aR = __builtin_amdgcn_mfma_f32_16x16x32_bf16(aH1, *(const short8v*)&sWf[(((g  )*2+1)*4+qd)*128 + ln*8], aR, 0,0,0);
        aZ = __builtin_amdgcn_mfma_f32_16x16x32_bf16(aH0, *(const short8v*)&sWf[(((3+g)*2+0)*4+qd)*128 + ln*8], aZ, 0,0,0);
        aZ = __builtin_amdgcn_mfma_f32_16x16x32_bf16(aH1, *(const short8v*)&sWf[(((3+g)*2+1)*4+qd)*128 + ln*8], aZ, 0,0,0);
        aN = __builtin_amdgcn_mfma_f32_16x16x32_bf16(aH0, *(const short8v*)&sWf[(((6+g)*2+0)*4+qd)*128 + ln*8], aN, 0,0,0);
        aN = __builtin_amdgcn_mfma_f32_16x16x32_bf16(aH1, *(const short8v*)&sWf[(((6+g)*2+1)*4+qd)*128 + ln*8], aN, 0,0,0);
        #pragma unroll
        for (int r = 0; r < 4; ++r){
          int row = qd*4 + r;
          float giR = bf2f(gIb[t*2304 + row*144 +      g*16 + ln]);
          float giZ = bf2f(gIb[t*2304 + row*144 + 48 + g*16 + ln]);
          float giN = bf2f(gIb[t*2304 + row*144 + 96 + g*16 + ln]);
          float rr = sigm(giR + biR + aR[r] + bhR);
          float zz = sigm(giZ + biZ + aZ[r] + bhZ);
          float nn = tanh_fast(giN + biN + rr*(aN[r] + bhN));
          float hv = (1.f-zz)*nn + zz*hold[r];
          hold[r] = hv;
          sw[row*72 + g*16 + ln] = f2bf(hv);
        }
      }
      __syncthreads();
    }
    // ---- stateP + q0 ----
    if (g < 3)
      #pragma unroll
      for (int r = 0; r < 4; ++r)
        stateP[(r0 + qd*4 + r)*48 + g*16 + ln] = hold[r];
    if (wid == 0){
      short8v aH0 = *(const short8v*)&sHb0[ln*72 + qd*8];
      short8v aH1 = *(const short8v*)&sHb0[ln*72 + 32 + qd*8];
      f32x4 q3[3];
      #pragma unroll
      for (int nt = 0; nt < 3; ++nt){
        q3[nt] = zf;
        q3[nt] = __builtin_amdgcn_mfma_f32_16x16x32_bf16(aH0, *(const short8v*)&WqF[((nt*2+0)*4+qd)*128 + ln*8], q3[nt], 0,0,0);
        q3[nt] = __builtin_amdgcn_mfma_f32_16x16x32_bf16(aH1, *(const short8v*)&WqF[((nt*2+1)*4+qd)*128 + ln*8], q3[nt], 0,0,0);
      }
      #pragma unroll
      for (int nt = 0; nt < 3; ++nt)
        #pragma unroll
        for (int r = 0; r < 4; ++r){
          int row = r0 + qd*4 + r, d = nt*16 + ln;
          float v = q3[nt][r] + bq[d];
          qf[row*48 + d] = v;
          qbB[row*64 + d] = f2bf(v * LOG2E);
        }
      #pragma unroll
      for (int r = 0; r < 4; ++r)
        if (ln < 8) *(u32*)&qbB[(r0+qd*4+r)*64 + 48 + ln*2] = 0;
    }
  } else {
    // ======== KV projection (512 tiles over 480 blocks) ========
    u16* sWkF = (u16*)(SMEM);
    u16* sWvF = (u16*)(SMEM + 6144);
    u16* smp  = (u16*)(SMEM + 12288 + wid*2304);
    u16* smf  = (u16*)(SMEM + 21504 + wid*2304);
    u16* sKT  = (u16*)(SMEM + 30720);
    u16* sVT  = (u16*)(SMEM + 38912);
    for (int i = wid; i < 6; i += 4) GLD_LDS((const char*)WkF + i*1024 + lane*16, SMEM + i*1024);
    for (int i = wid; i < 6; i += 4) GLD_LDS((const char*)WvF + i*1024 + lane*16, SMEM + 6144 + i*1024);
    float bkv[3], bvv[3];
    #pragma unroll
    for (int nt = 0; nt < 3; ++nt){ bkv[nt] = bk[nt*16+ln]; bvv[nt] = bv[nt*16+ln]; }
    int ntile = (bx < 32) ? 2 : 1;
    for (int tt = 0; tt < ntile; ++tt){
      int tile = (tt == 0) ? bx : (480 + bx);
      int r0 = tile*64 + wid*16;
      for (int i = lane; i < 576; i += 64){ ((u32*)smp)[i] = 0; ((u32*)smf)[i] = 0; }
      for (int i = lane; i < 768; i += 64){
        int r = i/48, c = i - r*48;
        smp[r*72+c] = f2bf(memory_past[(size_t)r0*48 + i]);
        smf[r*72+c] = f2bf(memory_fut[(size_t)r0*48 + i]);
      }
      __syncthreads();
      short8v aP0 = *(const short8v*)&smp[ln*72 + qd*8];
      short8v aP1 = *(const short8v*)&smp[ln*72 + 32 + qd*8];
      short8v aF0 = *(const short8v*)&smf[ln*72 + qd*8];
      short8v aF1 = *(const short8v*)&smf[ln*72 + 32 + qd*8];
      f32x4 k3[3], v3[3];
      #pragma unroll
      for (int nt = 0; nt < 3; ++nt){ k3[nt] = zf; v3[nt] = zf; }
      #pragma unroll
      for (int nt = 0; nt < 3; ++nt){
        k3[nt] = __builtin_amdgcn_mfma_f32_16x16x32_bf16(aP0, *(const short8v*)&sWkF[((nt*2+0)*4+qd)*128 + ln*8], k3[nt], 0,0,0);
        k3[nt] = __builtin_amdgcn_mfma_f32_16x16x32_bf16(aP1, *(const short8v*)&sWkF[((nt*2+1)*4+qd)*128 + ln*8], k3[nt], 0,0,0);
        v3[nt] = __builtin_amdgcn_mfma_f32_16x16x32_bf16(aF0, *(const short8v*)&sWvF[((nt*2+0)*4+qd)*128 + ln*8], v3[nt], 0,0,0);
        v3[nt] = __builtin_amdgcn_mfma_f32_16x16x32_bf16(aF1, *(const short8v*)&sWvF[((nt*2+1)*4+qd)*128 + ln*8], v3[nt], 0,0,0);
      }
      for (int i = lane; i < 128; i += 64) ((u32*)sKT)[(wid*16 + (i>>3))*32 + 24 + (i&7)] = 0;
      #pragma unroll
      for (int nt = 0; nt < 3; ++nt)
        #pragma unroll
        for (int r = 0; r < 4; ++r){
          int keyl = wid*16 + qd*4 + r, d = nt*16 + ln;
          sKT[keyl*64 + d] = f2bf(k3[nt][r] + bkv[nt]);
          sVT[d*72 + keyl] = f2bf(v3[nt][r] + bvv[nt]);
        }
      __syncthreads();
      for (int i = tid; i < 512; i += 256)
        *(uint4*)((char*)(Kb + (size_t)tile*64*64) + i*16) = *(const uint4*)((char*)sKT + i*16);
      for (int i = tid; i < 384; i += 256){
        int d = i>>3, sub = i&7;
        *(uint4*)((char*)(Vc + ((size_t)((tile*64)>>8)*48 + d)*256 + ((tile*64)&255)) + sub*16)
            = *(const uint4*)((char*)sVT + d*144 + sub*16);
      }
      __syncthreads();
    }
  }
}

// ---------------------------------------------------------------------------
// iter: [combine prev (bf16 partials) -> pred/q] + [flash partials cur (bf16)].
// grid 256 = 16 rowgroups(32 rows) x 16 chunks(2048 keys); 4 waves.
__global__ __launch_bounds__(256, 1) void iter_kernel(int mode, int it,
    const u16* qbB, const u16* Kb, const u16* Vc, const u16* WqF, const float* bq,
    const float* qfP, float* qfC, float* pred,
    const float* mP, const float* lP, const u16* aP,
    float* mC, float* lC, u16* aC)
{
  __shared__ __align__(16) char SMEM[55936];
  u16*   sQ  = (u16*)(SMEM + 45056);
  float* sWc = (float*)(SMEM + 49152);
  float* sLg = (float*)(SMEM + 51200);
  u16*   sCb = (u16*)(SMEM + 51332);
  const int tid = threadIdx.x, bx = blockIdx.x;
  const int wid = tid>>6, lane = tid&63, qd = lane>>4, ln = lane&15;
  const int rg = bx>>4, ch = bx&15;
  const int rowbase = rg*32;
  f32x4 zf = {0.f,0.f,0.f,0.f};

  if (mode == 1){
    float* sRed = (float*)SMEM;
    {
      int row = tid>>3, jj = tid&7, grow = rowbase + row;
      float m0 = mP[grow*16 + jj*2], m1 = mP[grow*16 + jj*2+1];
      float l0 = lP[grow*16 + jj*2], l1 = lP[grow*16 + jj*2+1];
      float mg = fmaxf(m0, m1);
      #pragma unroll
      for (int k = 1; k < 8; k <<= 1) mg = fmaxf(mg, __shfl_xor(mg, k));
      float w0 = exp2f(m0 - mg), w1 = exp2f(m1 - mg);
      float wl = w0*l0 + w1*l1;
      #pragma unroll
      for (int k = 1; k < 8; k <<= 1) wl += __shfl_xor(wl, k);
      sWc[row*16 + jj*2] = w0; sWc[row*16 + jj*2+1] = w1;
      if (jj == 0) sLg[row] = wl;
    }
    __syncthreads();
    {
      f32x4 accv[6];
      #pragma unroll
      for (int i = 0; i < 6; ++i) accv[i] = zf;
      #pragma unroll
      for (int ci = 0; ci < 4; ++ci){
        int c = wid*4 + ci;
        const u16* slab = aP + ((size_t)c*512 + rowbase)*48;
        #pragma unroll
        for (int i = 0; i < 6; ++i){
          int idx = i*64 + lane;
          uint2 u = *(const uint2*)&slab[idx*4];
          int rr = idx/12;
          float w = sWc[rr*16 + c];
          accv[i][0] += w*bflo(u.x); accv[i][1] += w*bfhi(u.x);
          accv[i][2] += w*bflo(u.y); accv[i][3] += w*bfhi(u.y);
        }
      }
      float* red = sRed + wid*1536;
      #pragma unroll
      for (int i = 0; i < 6; ++i)
        *(f32x4*)&red[(i*64 + lane)*4] = accv[i];
    }
    __syncthreads();
    {
      int row = tid>>3, jj = tid&7, grow = rowbase + row;
      float lg = sLg[row];
      int base = row*48 + jj*6;
      #pragma unroll
      for (int d6 = 0; d6 < 6; ++d6){
        int d = jj*6 + d6;
        float s = sRed[base+d6] + sRed[1536+base+d6] + sRed[3072+base+d6] + sRed[4608+base+d6];
        float a = s / lg;
        if (ch == 0) pred[(size_t)(grow*20 + (it-1))*48 + d] = a;
        sCb[row*72 + d] = f2bf(qfP[grow*48 + d] + a);
      }
      ((u32*)&sCb[row*72 + 48])[jj] = 0;
    }
    __syncthreads();
    if (wid < 2){
      short8v ac0 = *(const short8v*)&sCb[(wid*16+ln)*72 + qd*8];
      short8v ac1 = *(const short8v*)&sCb[(wid*16+ln)*72 + 32 + qd*8];
      f32x4 q3[3];
      #pragma unroll
      for (int nt = 0; nt < 3; ++nt){
        q3[nt] = zf;
        q3[nt] = __builtin_amdgcn_mfma_f32_16x16x32_bf16(ac0, *(const short8v*)&WqF[((nt*2+0)*4+qd)*128 + ln*8], q3[nt], 0,0,0);
        q3[nt] = __builtin_amdgcn_mfma_f32_16x16x32_bf16(ac1, *(const short8v*)&WqF[((nt*2+1)*4+qd)*128 + ln*8], q3[nt], 0,0,0);
      }
      #pragma unroll
      for (int nt = 0; nt < 3; ++nt)
        #pragma unroll
        for (int r = 0; r < 4; ++r){
          int lr = wid*16 + qd*4 + r, d = nt*16 + ln;
          float v = q3[nt][r] + bq[d];
          if (ch == 0) qfC[(rowbase + lr)*48 + d] = v;
          sQ[lr*64 + d] = f2bf(v * LOG2E);
        }
    } else {
      for (int i = tid-128; i < 256; i += 128){
        int r2 = i>>3, p = i&7;
        ((u32*)&sQ[r2*64 + 48])[p] = 0;
      }
    }
    __syncthreads();
  } else {
    const u32* src = (const u32*)(qbB + rowbase*64);
    ((u32*)sQ)[tid]       = src[tid];
    ((u32*)sQ)[256 + tid] = src[256 + tid];
    ((u32*)sQ)[512 + tid] = src[512 + tid];
    ((u32*)sQ)[768 + tid] = src[768 + tid];
    __syncthreads();
  }

  // ---- flash: wave handles 32 rows x 512 keys (8 kt of 64) ----
  const int wslice = ch*2048 + wid*512;
  u16* sp8 = (u16*)(SMEM + 26624);
  short8v aq[2][2];
  #pragma unroll
  for (int rt = 0; rt < 2; ++rt)
    #pragma unroll
    for (int kc = 0; kc < 2; ++kc)
      aq[rt][kc] = *(const short8v*)&sQ[(rt*16+ln)*64 + kc*32 + qd*8];
  f32x4 acc[2][3];
  #pragma unroll
  for (int rt = 0; rt < 2; ++rt) for (int dt = 0; dt < 3; ++dt) acc[rt][dt] = zf;
  float mrun[2] = {-3.0e38f, -3.0e38f}, lrun[2] = {0.f, 0.f};
  u16* spb[2] = { sp8 + (wid*2+0)*1152, sp8 + (wid*2+1)*1152 };

  #pragma unroll
  for (int kt = 0; kt < 8; ++kt){
    const int tb = wslice + kt*64;
    const u16* kb = Kb + (size_t)tb*64;
    const u16* vb = Vc + (size_t)(tb>>8)*48*256 + (tb & 255);
    short8v kf[4][2], vf[2][3];
    #pragma unroll
    for (int nt = 0; nt < 4; ++nt)
      #pragma unroll
      for (int kc = 0; kc < 2; ++kc)
        kf[nt][kc] = *(const short8v*)&kb[(nt*16+ln)*64 + kc*32 + qd*8];
    #pragma unroll
    for (int kc = 0; kc < 2; ++kc)
      #pragma unroll
      for (int dt = 0; dt < 3; ++dt)
        vf[kc][dt] = *(const short8v*)&vb[(dt*16+ln)*256 + kc*32 + qd*8];
    f32x4 s[2][4];
    #pragma unroll
    for (int rt = 0; rt < 2; ++rt)
      #pragma unroll
      for (int nt = 0; nt < 4; ++nt){
        f32x4 z = zf;
        z = __builtin_amdgcn_mfma_f32_16x16x32_bf16(kf[nt][0], aq[rt][0], z, 0,0,0);
        z = __builtin_amdgcn_mfma_f32_16x16x32_bf16(kf[nt][1], aq[rt][1], z, 0,0,0);
        s[rt][nt] = z;
      }
    #pragma unroll
    for (int rt = 0; rt < 2; ++rt){
      float vmax = fmaxf(fmaxf(fmaxf(s[rt][0][0], s[rt][0][1]), fmaxf(s[rt][0][2], s[rt][0][3])),
                   fmaxf(fmaxf(s[rt][1][0], s[rt][1][1]), fmaxf(s[rt][1][2], s[rt][1][3])));
      vmax = fmaxf(vmax, fmaxf(fmaxf(fmaxf(s[rt][2][0], s[rt][2][1]), fmaxf(s[rt][2][2], s[rt][2][3])),
                   fmaxf(fmaxf(s[rt][3][0], s[rt][3][1]), fmaxf(s[rt][3][2], s[rt][3][3]))));
      vmax = fmaxf(vmax, __shfl_xor(vmax, 16));
      vmax = fmaxf(vmax, __shfl_xor(vmax, 32));
      float mnew = fmaxf(mrun[rt], vmax);
      float alpha = exp2f(mrun[rt] - mnew);
      mrun[rt] = mnew;
      u16* sp = spb[rt];
      float lsum = 0.f;
      #pragma unroll
      for (int nt = 0; nt < 4; ++nt){
        float p0 = exp2f(s[rt][nt][0]-mnew), p1 = exp2f(s[rt][nt][1]-mnew);
        float p2 = exp2f(s[rt][nt][2]-mnew), p3 = exp2f(s[rt][nt][3]-mnew);
        lsum += (p0+p1)+(p2+p3);
        uint2 pk; pk.x = pk2(p0,p1); pk.y = pk2(p2,p3);
        *(uint2*)&sp[ln*72 + nt*16 + qd*4] = pk;
      }
      lsum += __shfl_xor(lsum, 16);
      lsum += __shfl_xor(lsum, 32);
      lrun[rt] = lrun[rt]*alpha + lsum;
      #pragma unroll
      for (int dt = 0; dt < 3; ++dt){
        acc[rt][dt][0] *= alpha; acc[rt][dt][1] *= alpha;
        acc[rt][dt][2] *= alpha; acc[rt][dt][3] *= alpha;
      }
      short8v pb0 = *(const short8v*)&sp[ln*72 + qd*8];
      short8v pb1 = *(const short8v*)&sp[ln*72 + 32 + qd*8];
      #pragma unroll
      for (int dt = 0; dt < 3; ++dt){
        acc[rt][dt] = __builtin_amdgcn_mfma_f32_16x16x32_bf16(vf[0][dt], pb0, acc[rt][dt], 0,0,0);
        acc[rt][dt] = __builtin_amdgcn_mfma_f32_16x16x32_bf16(vf[1][dt], pb1, acc[rt][dt], 0,0,0);
      }
    }
  }
  // ---- 4-wave merge -> bf16 partial per (row, chunk), slab layout ----
  __syncthreads();
  float* sMg = (float*)SMEM;
  #pragma unroll
  for (int rt = 0; rt < 2; ++rt)
    #pragma unroll
    for (int dt = 0; dt < 3; ++dt)
      #pragma unroll
      for (int r = 0; r < 4; ++r)
        sMg[wid*1600 + (rt*16+ln)*50 + dt*16 + qd*4 + r] = acc[rt][dt][r];
  if (lane < 16){
    sMg[wid*1600 + ln*50 + 48] = mrun[0]; sMg[wid*1600 + ln*50 + 49] = lrun[0];
    sMg[wid*1600 + (16+ln)*50 + 48] = mrun[1]; sMg[wid*1600 + (16+ln)*50 + 49] = lrun[1];
  }
  __syncthreads();
  {
    int row = tid>>3, jj = tid&7, grow = rowbase + row;
    float m0 = sMg[row*50+48], m1 = sMg[1600+row*50+48];
    float m2 = sMg[3200+row*50+48], m3 = sMg[4800+row*50+48];
    float mg = fmaxf(fmaxf(m0,m1), fmaxf(m2,m3));
    float e0 = exp2f(m0-mg), e1 = exp2f(m1-mg), e2 = exp2f(m2-mg), e3 = exp2f(m3-mg);
    float lg = e0*sMg[row*50+49] + e1*sMg[1600+row*50+49]
             + e2*sMg[3200+row*50+49] + e3*sMg[4800+row*50+49];
    if (jj == 0){ mC[grow*16 + ch] = mg; lC[grow*16 + ch] = lg; }
    int d0 = jj*6;
    float sv[6];
    #pragma unroll
    for (int d6 = 0; d6 < 6; ++d6){
      int d = d0 + d6;
      sv[d6] = e0*sMg[row*50+d] + e1*sMg[1600+row*50+d]
             + e2*sMg[3200+row*50+d] + e3*sMg[4800+row*50+d];
    }
    u16* ac = aC + ((size_t)ch*512 + grow)*48 + d0;
    *(u32*)&ac[0] = pk2(sv[0], sv[1]);
    *(u32*)&ac[2] = pk2(sv[2], sv[3]);
    *(u32*)&ac[4] = pk2(sv[4], sv[5]);
  }
}

// ---------------------------------------------------------------------------
// decoder: 12-step GRU(96); 640 blocks x 384 thr (6 waves); gate-slice split.
__global__ __launch_bounds__(384) void dec_kernel(
    const u16* Dihf, const u16* Dhhf, const float* b_ih, const float* b_hh,
    const float* stateP, const float* pred, const float* obs,
    const float* mF, const float* lF, const u16* aF,
    const float* fc_w, const float* fc_b, float* out)
{
  __shared__ __align__(16) u16 sx[2][16*104];
  __shared__ float sPx[2][6][16], sPy[2][6][16];
  const int tid = threadIdx.x, bx = blockIdx.x;
  const int wid = tid>>6, lane = tid&63, qd = lane>>4, ln = lane&15;
  const int rw = bx*16;
  f32x4 zf = {0.f,0.f,0.f,0.f};

  for (int i = tid; i < 1536; i += 384){
    int r = i/96, k = i - r*96;
    int row = rw + r, b20 = row/20;
    float v = (k < 48) ? stateP[b20*48 + k] : pred[(size_t)row*48 + (k-48)];
    sx[0][r*104 + k] = f2bf(v);
  }
  if (tid < 48){
    int r19 = (19 - (rw % 20)) % 20;
    if (r19 < 16){
      int b = (rw + r19)/20;
      float mg = -3.0e38f, mv[16];
      #pragma unroll
      for (int c = 0; c < 16; ++c){ mv[c] = mF[b*16 + c]; mg = fmaxf(mg, mv[c]); }
      float num = 0.f, den = 0.f;
      #pragma unroll
      for (int c = 0; c < 16; ++c){
        float w = exp2f(mv[c] - mg);
        den += w * lF[b*16 + c];
        num += w * bf2f(aF[((size_t)c*512 + b)*48 + tid]);
      }
      sx[0][r19*104 + 48 + tid] = f2bf(num/den);
    }
  }
  short8v whh[3][3];
  #pragma unroll
  for (int g = 0; g < 3; ++g)
    #pragma unroll
    for (int kc = 0; kc < 3; ++kc)
      whh[g][kc] = *(const short8v*)&Dhhf[(((g*6+wid)*3+kc)*4+qd)*128 + ln*8];
  const int d = wid*16 + ln;
  float biR=b_ih[d], biZ=b_ih[96+d], biN=b_ih[192+d];
  float bhR=b_hh[d], bhZ=b_hh[96+d], bhN=b_hh[192+d];
  float fw0=fc_w[d], fw1=fc_w[96+d];
  float hold[4] = {0.f,0.f,0.f,0.f};
  float fcb0 = fc_b[0], fcb1 = fc_b[1];
  float pres0 = 0.f, pres1 = 0.f;
  if (wid == 0 && lane < 16){
    int b20 = (rw + lane)/20;
    pres0 = obs[b20*16 + 14];
    pres1 = obs[b20*16 + 15];
  }
  __syncthreads();

  #pragma unroll 1
  for (int t = 0; t < 12; ++t){
    const u16* sr = sx[t&1];
    u16* sw = sx[(t+1)&1];
    short8v xa0 = *(const short8v*)&sr[ln*104 + qd*8];
    short8v xa1 = *(const short8v*)&sr[ln*104 + 32 + qd*8];
    short8v xa2 = *(const short8v*)&sr[ln*104 + 64 + qd*8];
    f32x4 acc[3] = {zf, zf, zf};
    if (t == 0){
      #pragma unroll
      for (int g = 0; g < 3; ++g){
        int nt = g*6 + wid;
        acc[g] = __builtin_amdgcn_mfma_f32_16x16x32_bf16(xa0, *(const short8v*)&Dihf[((nt*3+0)*4+qd)*128 + ln*8], acc[g], 0,0,0);
        acc[g] = __builtin_amdgcn_mfma_f32_16x16x32_bf16(xa1, *(const short8v*)&Dihf[((nt*3+1)*4+qd)*128 + ln*8], acc[g], 0,0,0);
        acc[g] = __builtin_amdgcn_mfma_f32_16x16x32_bf16(xa2, *(const short8v*)&Dihf[((nt*3+2)*4+qd)*128 + ln*8], acc[g], 0,0,0);
      }
    } else {
      #pragma unroll
      for (int g = 0; g < 3; ++g){
        acc[g] = __builtin_amdgcn_mfma_f32_16x16x32_bf16(xa0, whh[g][0], acc[g], 0,0,0);
        acc[g] = __builtin_amdgcn_mfma_f32_16x16x32_bf16(xa1, whh[g][1], acc[g], 0,0,0);
        acc[g] = __builtin_amdgcn_mfma_f32_16x16x32_bf16(xa2, whh[g][2], acc[g], 0,0,0);
      }
    }
    float px[4], py[4];
    #pragma unroll
    for (int r = 0; r < 4; ++r){
      float rr = sigm(acc[0][r] + biR + bhR);
      float zz = sigm(acc[1][r] + biZ + bhZ);
      float nn = (t == 0) ? tanh_fast(acc[2][r] + biN + rr*bhN)
                          : tanh_fast(biN + rr*(acc[2][r] + bhN));
      float hv = (1.f-zz)*nn + zz*hold[r];
      hold[r] = hv;
      sw[(qd*4+r)*104 + d] = f2bf(hv);
      px[r] = fw0*hv;
      py[r] = fw1*hv;
    }
    #pragma unroll
    for (int msk = 8; msk >= 1; msk >>= 1)
      #pragma unroll
      for (int r = 0; r < 4; ++r){
        px[r] += __shfl_xor(px[r], msk);
        py[r] += __shfl_xor(py[r], msk);
      }
    if (ln == 0){
      #pragma unroll
      for (int r = 0; r < 4; ++r){
        sPx[t&1][wid][qd*4+r] = px[r];
        sPy[t&1][wid][qd*4+r] = py[r];
      }
    }
    __syncthreads();
    if (wid == 0 && lane < 16){
      float fx = 0.f, fy = 0.f;
      #pragma unroll
      for (int w = 0; w < 6; ++w){ fx += sPx[t&1][w][lane]; fy += sPy[t&1][w][lane]; }
      pres0 += fx + fcb0;
      pres1 += fy + fcb1;
      out[((size_t)(rw + lane)*12 + t)*2 + 0] = pres0;
      out[((size_t)(rw + lane)*12 + t)*2 + 1] = pres1;
    }
  }
}

// ---------------------------------------------------------------------------
extern "C" void kernel_launch(void* const* d_in, const int* in_sizes, int n_in,
                              void* d_out, int out_size, void* d_ws, size_t ws_size,
                              hipStream_t stream)
{
  const float* past        = (const float*)d_in[0];
  const float* obs         = (const float*)d_in[1];
  const float* conv_w      = (const float*)d_in[2];
  const float* conv_b      = (const float*)d_in[3];
  const float* enc_w_ih    = (const float*)d_in[4];
  const float* enc_w_hh    = (const float*)d_in[5];
  const float* enc_b_ih    = (const float*)d_in[6];
  const float* enc_b_hh    = (const float*)d_in[7];
  const float* memory_past = (const float*)d_in[8];
  const float* memory_fut  = (const float*)d_in[9];
  const float* Wq = (const float*)d_in[10];
  const float* bq = (const float*)d_in[11];
  const float* Wk = (const float*)d_in[12];
  const float* bk = (const float*)d_in[13];
  const float* Wv = (const float*)d_in[14];
  const float* bv = (const float*)d_in[15];
  const float* dec_w_ih = (const float*)d_in[16];
  const float* dec_w_hh = (const float*)d_in[17];
  const float* dec_b_ih = (const float*)d_in[18];
  const float* dec_b_hh = (const float*)d_in[19];
  const float* fc_w = (const float*)d_in[20];
  const float* fc_b = (const float*)d_in[21];
  float* out = (float*)d_out;

  char* ws = (char*)d_ws;
  size_t off = 0;
  auto alloc = [&](size_t bytes){ void* p = ws + off; off += (bytes + 255) & ~(size_t)255; return p; };
  float* stateP = (float*)alloc(512*48*4);
  float* qfA    = (float*)alloc(512*48*4);
  float* qfB    = (float*)alloc(512*48*4);
  u16*   qbB    = (u16*)alloc(512*64*2);
  float* mB[2], *lB[2];
  u16*   aB[2];
  for (int i = 0; i < 2; ++i){
    mB[i] = (float*)alloc(512*16*4);
    lB[i] = (float*)alloc(512*16*4);
    aB[i] = (u16*)alloc((size_t)512*16*48*2);
  }
  float* pred = (float*)alloc((size_t)10240*48*4);
  u16*   Kb   = (u16*)alloc((size_t)32768*64*2);
  u16*   Vc   = (u16*)alloc((size_t)32768*48*2);
  u16*   Dihf = (u16*)alloc(27648*2);
  u16*   Dhhf = (u16*)alloc(27648*2);
  u16*   EihF = (u16*)alloc(9216*2);
  u16*   EhhF = (u16*)alloc(9216*2);
  u16*   WqF  = (u16*)alloc(3072*2);
  u16*   WkF  = (u16*)alloc(3072*2);
  u16*   WvF  = (u16*)alloc(3072*2);
  float* qbuf[2] = { qfA, qfB };

  prep_kernel<<<324, 256, 0, stream>>>(dec_w_ih, dec_w_hh, enc_w_ih, enc_w_hh,
                                       Wq, Wk, Wv, Dihf, Dhhf, EihF, EhhF, WqF, WkF, WvF);

  setup_kernel<<<512, 256, 0, stream>>>(
      past, conv_w, conv_b, enc_b_ih, enc_b_hh, memory_past, memory_fut,
      bq, bk, bv, EihF, EhhF, WqF, WkF, WvF,
      stateP, qfA, qbB, Kb, Vc);

  iter_kernel<<<256, 256, 0, stream>>>(0, 0, qbB, Kb, Vc, WqF, bq,
      qfA, qfA, pred, mB[1], lB[1], aB[1], mB[0], lB[0], aB[0]);
  for (int it = 1; it < 20; ++it){
    int pv = (it-1)&1, cu = it&1;
    iter_kernel<<<256, 256, 0, stream>>>(1, it, qbB, Kb, Vc, WqF, bq,
        qbuf[pv], qbuf[cu], pred, mB[pv], lB[pv], aB[pv], mB[cu], lB[cu], aB[cu]);
  }

  // it=19 wrote buffer index 1 -> dec consumes mB[1]/lB[1]/aB[1]
  dec_kernel<<<640, 384, 0, stream>>>(Dihf, Dhhf, dec_b_ih, dec_b_hh,
      stateP, pred, obs, mB[1], lB[1], aB[1], fc_w, fc_b, out);
}